// Round 13
// baseline (93.341 us; speedup 1.0000x reference)
//
#include <hip/hip_runtime.h>
#include <math.h>

// Problem constants (fixed by setup_inputs)
#define B_   16
#define C_   512
#define CR_  128
#define N_   4096
#define N4_  (N_ / 4)          // 1024 float4 per row
#define TN   32                // tile width in floats
#define TN4  (TN / 4)          // 8 float4 per tile-row
#define SUBT 2                 // subtiles per block (R7/R10 best-measured)
#define NTB  (N_ / TN / SUBT)  // 64 tile-blocks per batch -> 1024 blocks

static constexpr float BN_EPS_F = 1e-5f;

typedef float vfloat4 __attribute__((ext_vector_type(4)));

// ---------------------------------------------------------------------------
// K1f: fused colsum + att partials — EXACT R10 version (measured 22.3us).
// The R12 shfl-pre-reduce variant is reverted (suspected VGPR cliff).
// ---------------------------------------------------------------------------
__global__ __launch_bounds__(256) void k1f_att(
        const float* __restrict__ x,
        float* __restrict__ att_part) {
    const int ntb = blockIdx.x;          // [0, NTB)
    const int b   = blockIdx.y;          // [0, 16)
    const int t   = threadIdx.x;
    const int g   = t >> 3;              // [0, 32)
    const int i   = t & 7;               // [0, 8)

    __shared__ vfloat4 s_red[32][8];
    __shared__ vfloat4 s_tile4[8];

    const vfloat4* x4 = (const vfloat4*)x;
    float dacc[16];
#pragma unroll
    for (int st = 0; st < 16; ++st) dacc[st] = 0.f;

    for (int sub = 0; sub < SUBT; ++sub) {
        const int nt = ntb * SUBT + sub;
        const vfloat4* base = x4 + (size_t)b * C_ * N4_ + (size_t)nt * TN4;
        vfloat4 v[16];
        vfloat4 sacc = {0.f, 0.f, 0.f, 0.f};
#pragma unroll
        for (int st = 0; st < 16; ++st) {
            v[st] = base[(size_t)(st * 32 + g) * N4_ + i];
            sacc += v[st];
        }
        if (sub) __syncthreads();
        s_red[g][i] = sacc;
        __syncthreads();
        if (t < 8) {
            vfloat4 acc = {0.f, 0.f, 0.f, 0.f};
#pragma unroll
            for (int g2 = 0; g2 < 32; ++g2)
                acc += s_red[g2][t];
            s_tile4[t] = acc;
        }
        __syncthreads();
        const vfloat4 sv = s_tile4[i];
#pragma unroll
        for (int st = 0; st < 16; ++st)
            dacc[st] += v[st].x * sv.x + v[st].y * sv.y
                      + v[st].z * sv.z + v[st].w * sv.w;
    }

#pragma unroll
    for (int st = 0; st < 16; ++st) {
        float d = dacc[st];
        d += __shfl_xor(d, 1, 64);
        d += __shfl_xor(d, 2, 64);
        d += __shfl_xor(d, 4, 64);
        dacc[st] = d;
    }
    if (i == 0) {
        float* dst = att_part + ((size_t)ntb * B_ + b) * C_;
#pragma unroll
        for (int st = 0; st < 16; ++st)
            dst[st * 32 + g] = dacc[st];
    }
}

// ---------------------------------------------------------------------------
// K23: fused att-reduce + dense1+BN+ReLU + dense2+sigmoid (R12 version,
// kept unchanged for the A/B).  16 blocks x 1024 threads.
// ---------------------------------------------------------------------------
__global__ __launch_bounds__(1024) void k23(
        const float* __restrict__ att_part,
        const float* __restrict__ W1,
        const float* __restrict__ gamma,
        const float* __restrict__ beta,
        const float* __restrict__ rmean,
        const float* __restrict__ rvar,
        const float* __restrict__ W2,
        float* __restrict__ a) {
    __shared__ float att_s[C_];
    __shared__ float h_s[CR_];
    const int b = blockIdx.x;
    const int t = threadIdx.x;
    const int w = t >> 6;        // wave [0,16)
    const int lane = t & 63;

    // P1: partial reduce (coalesced in c)
    if (t < C_) {
        float acc = 0.f;
#pragma unroll 8
        for (int nb = 0; nb < NTB; ++nb)
            acc += att_part[((size_t)nb * B_ + b) * C_ + t];
        att_s[t] = acc;
    }
    __syncthreads();

    // P2: dense1 + BN + ReLU.  16 waves x 8 outputs.
#pragma unroll
    for (int oo = 0; oo < 8; ++oo) {
        const int o = w * 8 + oo;
        const float* wp = W1 + (size_t)o * C_;
        float acc = 0.f;
#pragma unroll
        for (int k = 0; k < C_ / 64; ++k)
            acc += wp[k * 64 + lane] * att_s[k * 64 + lane];
#pragma unroll
        for (int off = 32; off >= 1; off >>= 1)
            acc += __shfl_down(acc, off, 64);
        if (lane == 0) {
            float v = gamma[o] * (acc - rmean[o]) * rsqrtf(rvar[o] + BN_EPS_F) + beta[o];
            h_s[o] = fmaxf(v, 0.f);
        }
    }
    __syncthreads();

    // P3: dense2 + sigmoid.  16 waves x 32 outputs.
#pragma unroll
    for (int jj = 0; jj < 32; ++jj) {
        const int j = w * 32 + jj;
        const float* wp = W2 + (size_t)j * CR_;
        float acc = wp[lane] * h_s[lane] + wp[64 + lane] * h_s[64 + lane];
#pragma unroll
        for (int off = 32; off >= 1; off >>= 1)
            acc += __shfl_down(acc, off, 64);
        if (lane == 0) a[(size_t)b * C_ + j] = 1.f / (1.f + expf(-acc));
    }
}

// ---------------------------------------------------------------------------
// K4: out = x * a[row].  Block-per-row, NT stores.  Measured 38.8us — at
// the r+w ceiling (above the 6.29 TB/s D2D copy benchmark); do not touch.
// ---------------------------------------------------------------------------
__global__ __launch_bounds__(256) void k4_scale(
        const float* __restrict__ x,
        const float* __restrict__ a,
        float* __restrict__ out) {
    const int row = blockIdx.x;          // [0, B*C)
    const float av = a[row];
    const vfloat4* xr = (const vfloat4*)x + (size_t)row * N4_;
    vfloat4* orow     = (vfloat4*)out     + (size_t)row * N4_;
#pragma unroll
    for (int it = 0; it < N4_ / 256; ++it) {   // 4 iters
        const int idx = it * 256 + threadIdx.x;
        vfloat4 ov = xr[idx] * av;
        __builtin_nontemporal_store(ov, &orow[idx]);
    }
}

// ---------------------------------------------------------------------------
extern "C" void kernel_launch(void* const* d_in, const int* in_sizes, int n_in,
                              void* d_out, int out_size, void* d_ws, size_t ws_size,
                              hipStream_t stream) {
    const float* x     = (const float*)d_in[0];
    const float* W1    = (const float*)d_in[1];
    const float* gamma = (const float*)d_in[2];
    const float* beta  = (const float*)d_in[3];
    const float* rmean = (const float*)d_in[4];
    const float* rvar  = (const float*)d_in[5];
    const float* W2    = (const float*)d_in[6];
    float* out = (float*)d_out;

    // Workspace (floats): att_part 64*16*512 = 524288 (2 MiB), a 8192
    float* ws       = (float*)d_ws;
    float* att_part = ws;
    float* a        = att_part + (size_t)NTB * B_ * C_;

    k1f_att<<<dim3(NTB, B_), 256, 0, stream>>>(x, att_part);
    k23<<<dim3(B_), 1024, 0, stream>>>(att_part, W1, gamma, beta, rmean, rvar, W2, a);
    k4_scale<<<dim3(B_ * C_), 256, 0, stream>>>(x, a, out);
}

// Round 14
// 73.209 us; speedup vs baseline: 1.2750x; 1.2750x over previous
//
#include <hip/hip_runtime.h>
#include <math.h>

// Problem constants (fixed by setup_inputs)
#define B_   16
#define C_   512
#define CR_  128
#define N_   4096
#define N4_  (N_ / 4)          // 1024 float4 per row
#define TN   32                // tile width in floats
#define TN4  (TN / 4)          // 8 float4 per tile-row
#define SUBT 2                 // subtiles per block (R7/R10 best-measured)
#define NTB  (N_ / TN / SUBT)  // 64 tile-blocks per batch -> 1024 blocks

static constexpr float BN_EPS_F = 1e-5f;

typedef float vfloat4 __attribute__((ext_vector_type(4)));

// ---------------------------------------------------------------------------
// K1f: fused colsum + att partials — EXACT R10 version (measured 22.3us).
// ---------------------------------------------------------------------------
__global__ __launch_bounds__(256) void k1f_att(
        const float* __restrict__ x,
        float* __restrict__ att_part) {
    const int ntb = blockIdx.x;          // [0, NTB)
    const int b   = blockIdx.y;          // [0, 16)
    const int t   = threadIdx.x;
    const int g   = t >> 3;              // [0, 32)
    const int i   = t & 7;               // [0, 8)

    __shared__ vfloat4 s_red[32][8];
    __shared__ vfloat4 s_tile4[8];

    const vfloat4* x4 = (const vfloat4*)x;
    float dacc[16];
#pragma unroll
    for (int st = 0; st < 16; ++st) dacc[st] = 0.f;

    for (int sub = 0; sub < SUBT; ++sub) {
        const int nt = ntb * SUBT + sub;
        const vfloat4* base = x4 + (size_t)b * C_ * N4_ + (size_t)nt * TN4;
        vfloat4 v[16];
        vfloat4 sacc = {0.f, 0.f, 0.f, 0.f};
#pragma unroll
        for (int st = 0; st < 16; ++st) {
            v[st] = base[(size_t)(st * 32 + g) * N4_ + i];
            sacc += v[st];
        }
        if (sub) __syncthreads();
        s_red[g][i] = sacc;
        __syncthreads();
        if (t < 8) {
            vfloat4 acc = {0.f, 0.f, 0.f, 0.f};
#pragma unroll
            for (int g2 = 0; g2 < 32; ++g2)
                acc += s_red[g2][t];
            s_tile4[t] = acc;
        }
        __syncthreads();
        const vfloat4 sv = s_tile4[i];
#pragma unroll
        for (int st = 0; st < 16; ++st)
            dacc[st] += v[st].x * sv.x + v[st].y * sv.y
                      + v[st].z * sv.z + v[st].w * sv.w;
    }

#pragma unroll
    for (int st = 0; st < 16; ++st) {
        float d = dacc[st];
        d += __shfl_xor(d, 1, 64);
        d += __shfl_xor(d, 2, 64);
        d += __shfl_xor(d, 4, 64);
        dacc[st] = d;
    }
    if (i == 0) {
        float* dst = att_part + ((size_t)ntb * B_ + b) * C_;
#pragma unroll
        for (int st = 0; st < 16; ++st)
            dst[st * 32 + g] = dacc[st];
    }
}

// ---------------------------------------------------------------------------
// K2r: att[b,c] = sum_nb att_part[nb][b][c].  8192 threads, coalesced in c.
// (R10-exact)
// ---------------------------------------------------------------------------
__global__ __launch_bounds__(256) void k2r(
        const float* __restrict__ att_part,
        float* __restrict__ att) {
    const int g = blockIdx.x * 256 + threadIdx.x;   // [0, B*C)
    float acc = 0.f;
#pragma unroll 8
    for (int nb = 0; nb < NTB; ++nb)
        acc += att_part[(size_t)nb * (B_ * C_) + g];
    att[g] = acc;
}

// ---------------------------------------------------------------------------
// K3a: h[b,o] = relu(BN(sum_c W1[o,c]*att[b,c])).  Wave per output.
// (R10-exact)
// ---------------------------------------------------------------------------
__global__ __launch_bounds__(256) void k3a(
        const float* __restrict__ W1,
        const float* __restrict__ att,
        const float* __restrict__ gamma,
        const float* __restrict__ beta,
        const float* __restrict__ rmean,
        const float* __restrict__ rvar,
        float* __restrict__ h) {
    const int wave = threadIdx.x >> 6;
    const int lane = threadIdx.x & 63;
    const int idx  = blockIdx.x * 4 + wave;   // [0, B*CR)
    const int b = idx >> 7;
    const int o = idx & (CR_ - 1);
    const float* w  = W1  + (size_t)o * C_;
    const float* at = att + (size_t)b * C_;
    float acc = 0.f;
#pragma unroll
    for (int k = 0; k < C_ / 64; ++k)         // 8 iters
        acc += w[k * 64 + lane] * at[k * 64 + lane];
#pragma unroll
    for (int off = 32; off >= 1; off >>= 1)
        acc += __shfl_down(acc, off, 64);
    if (lane == 0) {
        float v = gamma[o] * (acc - rmean[o]) * rsqrtf(rvar[o] + BN_EPS_F) + beta[o];
        h[idx] = fmaxf(v, 0.f);
    }
}

// ---------------------------------------------------------------------------
// K4f: fused k3b + k4.  Block-per-row (row = b*512+j).  Every wave
// redundantly computes a[b,j] = sigmoid(dot128(W2[j,:], h[b,:])) — W2/h are
// L2-hot, the dot hides under the block's x HBM loads, no barrier needed
// (per-wave __shfl broadcast).  Then out[row,:] = x[row,:] * a.
// ---------------------------------------------------------------------------
__global__ __launch_bounds__(256) void k4f(
        const float* __restrict__ x,
        const float* __restrict__ W2,
        const float* __restrict__ h,
        float* __restrict__ out) {
    const int row  = blockIdx.x;         // [0, B*C)
    const int b    = row >> 9;
    const int j    = row & (C_ - 1);
    const int t    = threadIdx.x;
    const int lane = t & 63;

    // issue the row's x loads first (HBM, ~900cy)
    const vfloat4* xr = (const vfloat4*)x + (size_t)row * N4_;
    vfloat4 xv[4];
#pragma unroll
    for (int it = 0; it < 4; ++it)
        xv[it] = xr[it * 256 + t];

    // per-wave redundant 128-dot (L2-hot operands) while x is in flight
    const float* wp = W2 + (size_t)j * CR_;
    const float* hp = h  + (size_t)b * CR_;
    float acc = wp[lane] * hp[lane] + wp[64 + lane] * hp[64 + lane];
#pragma unroll
    for (int off = 32; off >= 1; off >>= 1)
        acc += __shfl_down(acc, off, 64);
    float av = __shfl(acc, 0, 64);
    av = 1.f / (1.f + expf(-av));

    vfloat4* orow = (vfloat4*)out + (size_t)row * N4_;
#pragma unroll
    for (int it = 0; it < 4; ++it)
        __builtin_nontemporal_store(xv[it] * av, &orow[it * 256 + t]);
}

// ---------------------------------------------------------------------------
extern "C" void kernel_launch(void* const* d_in, const int* in_sizes, int n_in,
                              void* d_out, int out_size, void* d_ws, size_t ws_size,
                              hipStream_t stream) {
    const float* x     = (const float*)d_in[0];
    const float* W1    = (const float*)d_in[1];
    const float* gamma = (const float*)d_in[2];
    const float* beta  = (const float*)d_in[3];
    const float* rmean = (const float*)d_in[4];
    const float* rvar  = (const float*)d_in[5];
    const float* W2    = (const float*)d_in[6];
    float* out = (float*)d_out;

    // Workspace (floats): att_part 64*16*512 = 524288 (2 MiB),
    // att 8192, h 2048
    float* ws       = (float*)d_ws;
    float* att_part = ws;
    float* att      = att_part + (size_t)NTB * B_ * C_;
    float* h        = att + (size_t)B_ * C_;

    k1f_att<<<dim3(NTB, B_), 256, 0, stream>>>(x, att_part);
    k2r<<<dim3(B_ * C_ / 256), 256, 0, stream>>>(att_part, att);
    k3a<<<dim3(B_ * CR_ / 4), 256, 0, stream>>>(W1, att, gamma, beta, rmean, rvar, h);
    k4f<<<dim3(B_ * C_), 256, 0, stream>>>(x, W2, h, out);
}